// Round 4
// baseline (1315.678 us; speedup 1.0000x reference)
//
#include <hip/hip_runtime.h>
#include <hip/hip_bf16.h>
#include <stdint.h>

// ---------------------------------------------------------------------------
// InterFusion, fp32 I/O (per reference dtypes): LN1 -> QKV(fused N=3072) ->
// attn(S=2) -> O-proj(+resid, fp32 out1 -> d_out) -> LN2 -> FFN1 -> FFN2
// (+fp32 RMW residual on d_out). Compute: bf16 MFMA 16x16x32, fp32 acc.
// Weights converted fp32->bf16 into workspace each launch (idempotent).
// Workspace peak 32 MiB.
// ---------------------------------------------------------------------------

typedef __attribute__((ext_vector_type(8))) short short8;   // 8 bf16 = 4 VGPR
typedef __attribute__((ext_vector_type(4))) float floatx4;  // MFMA acc

__device__ __forceinline__ float b2f(short s) {
  union { unsigned u; float f; } v;
  v.u = ((unsigned)(unsigned short)s) << 16;
  return v.f;
}
__device__ __forceinline__ short f2b(float f) {
  union { float f; unsigned u; } v;
  v.f = f;
  unsigned r = v.u + 0x7FFFu + ((v.u >> 16) & 1u);  // RNE
  return (short)(r >> 16);
}
__device__ __forceinline__ float fast_tanh(float x) {
  float e = __expf(2.f * x);
  return 1.f - 2.f / (e + 1.f);
}

// ---------------------------------------------------------------------------
// fp32 -> bf16 conversion, 8 elems/thread.
// ---------------------------------------------------------------------------
__global__ __launch_bounds__(256) void cvt_kernel(const float* __restrict__ x,
                                                  short* __restrict__ y,
                                                  int n8) {
  const int i = blockIdx.x * 256 + threadIdx.x;
  if (i >= n8) return;
  const float4 a = ((const float4*)x)[(size_t)i * 2];
  const float4 b = ((const float4*)x)[(size_t)i * 2 + 1];
  short8 r;
  r[0] = f2b(a.x); r[1] = f2b(a.y); r[2] = f2b(a.z); r[3] = f2b(a.w);
  r[4] = f2b(b.x); r[5] = f2b(b.y); r[6] = f2b(b.z); r[7] = f2b(b.w);
  ((short8*)y)[i] = r;
}

// ---------------------------------------------------------------------------
// GEMM: C[M,N] = A[M,K] @ W[N,K]^T  (bf16 in, fp32 acc), epilogue variants.
// grid = (N/128, M/128), block = 256 (4 waves, 2x2 of 64x64 per wave).
// EPI 0: store bf16
// EPI 1: c + aux_f32[r][n], store fp32
// EPI 2: tanh(c + bias_f32[n]), store bf16
// EPI 3: tanh(c + bias_f32[n]) + res_f32[r][n], store fp32 (res MAY ALIAS C)
// ---------------------------------------------------------------------------
#define LDS_STRIDE 72  // 64 shorts data + 8 pad

template <int EPI>
__global__ __launch_bounds__(256) void gemm_bt(
    const short* A, int lda, const short* W, int K, void* Cout, int ldc,
    const float* aux, int ld_aux, const float* bias, const float* res,
    int ldr) {
  __shared__ short As[128 * LDS_STRIDE];
  __shared__ short Bs[128 * LDS_STRIDE];
  const int tid = threadIdx.x;
  const int lane = tid & 63;
  const int wid = tid >> 6;
  const int l15 = lane & 15;
  const int l4 = lane >> 4;
  const int wm = (wid >> 1) * 64;
  const int wn = (wid & 1) * 64;
  const int bn0 = blockIdx.x * 128;
  const int bm0 = blockIdx.y * 128;
  const int srow = tid >> 3;  // staging row within 32-row group
  const int sg = tid & 7;     // staging k-granule (8 shorts)

  floatx4 zero = {0.f, 0.f, 0.f, 0.f};
  floatx4 acc[4][4];
#pragma unroll
  for (int i = 0; i < 4; ++i)
#pragma unroll
    for (int j = 0; j < 4; ++j) acc[i][j] = zero;

  const short* Aptr = A + (size_t)(bm0 + srow) * lda + sg * 8;
  const short* Wptr = W + (size_t)(bn0 + srow) * K + sg * 8;

  for (int k0 = 0; k0 < K; k0 += 64) {
    short8 ar[4], br[4];
#pragma unroll
    for (int p = 0; p < 4; ++p) {
      ar[p] = *(const short8*)(Aptr + (size_t)p * 32 * lda + k0);
      br[p] = *(const short8*)(Wptr + (size_t)p * 32 * K + k0);
    }
#pragma unroll
    for (int p = 0; p < 4; ++p) {
      *(short8*)&As[(p * 32 + srow) * LDS_STRIDE + sg * 8] = ar[p];
      *(short8*)&Bs[(p * 32 + srow) * LDS_STRIDE + sg * 8] = br[p];
    }
    __syncthreads();
#pragma unroll
    for (int kk = 0; kk < 2; ++kk) {
      const int ko = (kk * 4 + l4) * 8;
      short8 av[4], bv[4];
#pragma unroll
      for (int i = 0; i < 4; ++i) {
        av[i] = *(const short8*)&As[(wm + i * 16 + l15) * LDS_STRIDE + ko];
        bv[i] = *(const short8*)&Bs[(wn + i * 16 + l15) * LDS_STRIDE + ko];
      }
#pragma unroll
      for (int i = 0; i < 4; ++i)
#pragma unroll
        for (int j = 0; j < 4; ++j)
          acc[i][j] = __builtin_amdgcn_mfma_f32_16x16x32_bf16(av[i], bv[j],
                                                              acc[i][j], 0, 0, 0);
    }
    __syncthreads();
  }

  // epilogue: lane holds C[mb + i*16 + p][nb + j*16], p = 0..3
  const int mb = bm0 + wm + l4 * 4;
  const int nb = bn0 + wn + l15;
#pragma unroll
  for (int i = 0; i < 4; ++i) {
#pragma unroll
    for (int p = 0; p < 4; ++p) {
      const int r = mb + i * 16 + p;
#pragma unroll
      for (int j = 0; j < 4; ++j) {
        const int n = nb + j * 16;
        float c = acc[i][j][p];
        if (EPI == 0) {
          ((short*)Cout)[(size_t)r * ldc + n] = f2b(c);
        } else if (EPI == 1) {
          ((float*)Cout)[(size_t)r * ldc + n] =
              c + aux[(size_t)r * ld_aux + n];
        } else if (EPI == 2) {
          ((short*)Cout)[(size_t)r * ldc + n] = f2b(fast_tanh(c + bias[n]));
        } else {
          const float rv = res[(size_t)r * ldr + n];  // load BEFORE store
          ((float*)Cout)[(size_t)r * ldc + n] = fast_tanh(c + bias[n]) + rv;
        }
      }
    }
  }
}

// ---------------------------------------------------------------------------
// LayerNorm over (S,E) = 2048 fp32 elems per batch b. One block per b.
// fp32 in, bf16 out. w/b fp32 (length 2048).
// ---------------------------------------------------------------------------
__global__ __launch_bounds__(256) void ln_kernel(const float* __restrict__ x,
                                                 const float* __restrict__ w,
                                                 const float* __restrict__ bb,
                                                 short* __restrict__ y) {
  const int b = blockIdx.x;
  const int tid = threadIdx.x;
  const size_t base = (size_t)b * 2048 + tid * 8;
  float xv[8];
  {
    const float4 a = *(const float4*)(x + base);
    const float4 c = *(const float4*)(x + base + 4);
    xv[0] = a.x; xv[1] = a.y; xv[2] = a.z; xv[3] = a.w;
    xv[4] = c.x; xv[5] = c.y; xv[6] = c.z; xv[7] = c.w;
  }
  float sum = 0.f, sq = 0.f;
#pragma unroll
  for (int j = 0; j < 8; ++j) {
    sum += xv[j];
    sq += xv[j] * xv[j];
  }
  __shared__ float rs[8];
  const int lane = tid & 63, wid = tid >> 6;
#pragma unroll
  for (int off = 32; off; off >>= 1) {
    sum += __shfl_down(sum, off);
    sq += __shfl_down(sq, off);
  }
  if (lane == 0) {
    rs[wid] = sum;
    rs[4 + wid] = sq;
  }
  __syncthreads();
  const float stot = rs[0] + rs[1] + rs[2] + rs[3];
  const float qtot = rs[4] + rs[5] + rs[6] + rs[7];
  const float mean = stot * (1.f / 2048.f);
  const float rstd = rsqrtf(qtot * (1.f / 2048.f) - mean * mean + 1e-5f);
  const int wi = tid * 8;
  short8 r;
#pragma unroll
  for (int j = 0; j < 8; ++j)
    r[j] = f2b((xv[j] - mean) * rstd * w[wi + j] + bb[wi + j]);
  *(short8*)(y + base) = r;
}

// ---------------------------------------------------------------------------
// Attention, S=2, on the fused QKV buffer (row stride 3072: q|k|v columns).
// q[b,h,s,d] = qkv[b*2+s][d*16+h]; scores (2x2)/8; softmax over t;
// concat[b,s,e] = p0*v[b,0,e] + p1*v[b,1,e], h = e&15. concat overwrites the
// q columns in-place (rows LDS-buffered first; block-private b's).
// Block=256 handles 2 b's (128 threads each).
// ---------------------------------------------------------------------------
__global__ __launch_bounds__(256) void attn_kernel(short* qkv) {
  __shared__ short sm[2][6][1032];    // q0,q1,k0,k1,v0,v1
  __shared__ float sps[2][2][2][16];  // [half][s][t][h] scores
  __shared__ float spp[2][2][2][16];  // [half][s][t][h] probs
  const int tid = threadIdx.x;
  const int half = tid >> 7;
  const int t = tid & 127;
  const int b = blockIdx.x * 2 + half;
  const short* row0 = qkv + ((size_t)b * 2 + 0) * 3072;
  const short* row1 = qkv + ((size_t)b * 2 + 1) * 3072;
  const short* srcs[6] = {row0,        row1,        row0 + 1024,
                          row1 + 1024, row0 + 2048, row1 + 2048};
#pragma unroll
  for (int rr = 0; rr < 6; ++rr)
    *(short8*)&sm[half][rr][t * 8] = *(const short8*)(srcs[rr] + t * 8);
  __syncthreads();
  if (t < 64) {
    const int h = t & 15, comb = t >> 4;
    const int si = comb >> 1, ti = comb & 1;
    const short* qr = sm[half][si];
    const short* kr = sm[half][2 + ti];
    float a = 0.f;
#pragma unroll
    for (int d = 0; d < 64; ++d) a += b2f(qr[d * 16 + h]) * b2f(kr[d * 16 + h]);
    sps[half][si][ti][h] = a * 0.125f;  // / sqrt(NH=64)
  }
  __syncthreads();
  if (t < 32) {
    const int h = t & 15, si = t >> 4;
    const float s0 = sps[half][si][0][h], s1 = sps[half][si][1][h];
    const float m = fmaxf(s0, s1);
    const float e0 = __expf(s0 - m), e1 = __expf(s1 - m);
    const float inv = 1.f / (e0 + e1);
    spp[half][si][0][h] = e0 * inv;
    spp[half][si][1][h] = e1 * inv;
  }
  __syncthreads();
#pragma unroll
  for (int si = 0; si < 2; ++si) {
    short8 r;
#pragma unroll
    for (int j = 0; j < 8; ++j) {
      const int e = t * 8 + j;
      const int h = e & 15;
      const float c = spp[half][si][0][h] * b2f(sm[half][4][e]) +
                      spp[half][si][1][h] * b2f(sm[half][5][e]);
      r[j] = f2b(c);
    }
    *(short8*)(qkv + ((size_t)b * 2 + si) * 3072 + t * 8) = r;  // over q cols
  }
}

// ---------------------------------------------------------------------------
extern "C" void kernel_launch(void* const* d_in, const int* in_sizes, int n_in,
                              void* d_out, int out_size, void* d_ws,
                              size_t ws_size, hipStream_t stream) {
  (void)in_sizes; (void)n_in; (void)out_size; (void)ws_size;
  const float* input = (const float*)d_in[0];
  const float* Wq = (const float*)d_in[1];
  const float* Wk = (const float*)d_in[2];
  const float* Wv = (const float*)d_in[3];
  const float* Wo = (const float*)d_in[4];
  const float* ln1w = (const float*)d_in[5];
  const float* ln1b = (const float*)d_in[6];
  const float* ln2w = (const float*)d_in[7];
  const float* ln2b = (const float*)d_in[8];
  const float* f1w1 = (const float*)d_in[9];
  const float* f1b1 = (const float*)d_in[10];
  const float* f1w2 = (const float*)d_in[11];
  const float* f1b2 = (const float*)d_in[12];
  const float* f2w1 = (const float*)d_in[13];
  const float* f2b1 = (const float*)d_in[14];
  const float* f2w2 = (const float*)d_in[15];
  const float* f2b2 = (const float*)d_in[16];
  float* out = (float*)d_out;
  char* ws = (char*)d_ws;

  const size_t MB = 1024 * 1024;
  dim3 blk(256);

  // ---- Phase 1: LN1 -> fused QKV -> attn -> O-proj(+resid) ---------------
  // ws: wqkv [0,6) wo [6,8) | per chunk: xs [8,12) qkv [12,24)   (peak 24 MiB)
  {
    short* wqkv = (short*)ws;                    // 3072 x 1024 bf16
    short* wo = (short*)(ws + 6 * MB);           // 1024 x 1024 bf16
    short* xs = (short*)(ws + 8 * MB);           // 2048 x 1024 bf16
    short* qkvb = (short*)(ws + 12 * MB);        // 2048 x 3072 bf16
    cvt_kernel<<<512, blk, 0, stream>>>(Wq, wqkv, 131072);
    cvt_kernel<<<512, blk, 0, stream>>>(Wk, wqkv + 1024 * 1024, 131072);
    cvt_kernel<<<512, blk, 0, stream>>>(Wv, wqkv + 2 * 1024 * 1024, 131072);
    cvt_kernel<<<512, blk, 0, stream>>>(Wo, wo, 131072);
    const int CH_B = 1024;       // batches per chunk
    const int CH_R = CH_B * 2;   // rows per chunk
    for (int c = 0; c < 8; ++c) {
      const float* inp_c = input + (size_t)c * CH_R * 1024;
      float* out_c = out + (size_t)c * CH_R * 1024;
      ln_kernel<<<CH_B, blk, 0, stream>>>(inp_c, ln1w, ln1b, xs);
      dim3 gqkv(24, CH_R / 128);  // N=3072
      gemm_bt<0><<<gqkv, blk, 0, stream>>>(xs, 1024, wqkv, 1024, qkvb, 3072,
                                           nullptr, 0, nullptr, nullptr, 0);
      attn_kernel<<<CH_B / 2, blk, 0, stream>>>(qkvb);
      dim3 go(8, CH_R / 128);  // N=1024
      // out1 = concat @ Wo^T + input  (fp32) -> d_out
      gemm_bt<1><<<go, blk, 0, stream>>>(qkvb, 3072, wo, 1024, out_c, 1024,
                                         inp_c, 1024, nullptr, nullptr, 0);
    }
  }

  // ---- Phase 2: LN2 -> FFN1 -> FFN2(+resid RMW on d_out) -----------------
  // ws: fw1[2] [0,8) fw2[2] [8,16) | outs [16,24) hb [24,32)  (peak 32 MiB)
  {
    short* fw1s[2] = {(short*)ws, (short*)(ws + 4 * MB)};       // 2048x1024
    short* fw2s[2] = {(short*)(ws + 8 * MB), (short*)(ws + 12 * MB)};  // 1024x2048
    short* outs = (short*)(ws + 16 * MB);  // 2048 x 2048 bf16
    short* hb = (short*)(ws + 24 * MB);    // 2048 x 2048 bf16
    cvt_kernel<<<1024, blk, 0, stream>>>(f1w1, fw1s[0], 262144);
    cvt_kernel<<<1024, blk, 0, stream>>>(f2w1, fw1s[1], 262144);
    cvt_kernel<<<1024, blk, 0, stream>>>(f1w2, fw2s[0], 262144);
    cvt_kernel<<<1024, blk, 0, stream>>>(f2w2, fw2s[1], 262144);
    const float* b1s[2] = {f1b1, f2b1};
    const float* b2s[2] = {f1b2, f2b2};
    const int CH_B = 2048;  // batches per chunk
    for (int c = 0; c < 4; ++c) {
      float* out_c = out + (size_t)c * CH_B * 2048;
      ln_kernel<<<CH_B, blk, 0, stream>>>(out_c, ln2w, ln2b, outs);
      for (int s = 0; s < 2; ++s) {
        dim3 g1(16, CH_B / 128);  // N=2048
        dim3 g2(8, CH_B / 128);   // N=1024
        // h = tanh(outs_s @ w1^T + b1)  (bf16)
        gemm_bt<2><<<g1, blk, 0, stream>>>(outs + s * 1024, 2048, fw1s[s],
                                           1024, hb, 2048, nullptr, 0, b1s[s],
                                           nullptr, 0);
        // out = tanh(h @ w2^T + b2) + out1   (fp32 RMW on d_out)
        gemm_bt<3><<<g2, blk, 0, stream>>>(hb, 2048, fw2s[s], 2048,
                                           out_c + s * 1024, 2048, nullptr, 0,
                                           b2s[s], out_c + s * 1024, 2048);
      }
    }
  }
}

// Round 5
// 698.397 us; speedup vs baseline: 1.8839x; 1.8839x over previous
//
#include <hip/hip_runtime.h>
#include <hip/hip_bf16.h>
#include <stdint.h>

// ---------------------------------------------------------------------------
// InterFusion, fp32 I/O: LN1 -> QKV(fused N=3072) -> attn(S=2) ->
// O-proj(+resid, fp32 -> d_out) -> LN2 -> FFN1 -> FFN2 (+fp32 RMW on d_out).
// Compute: bf16 MFMA 16x16x32, fp32 acc. m97-style global_load_lds staging.
// Chunk sizes adapt to ws_size (>=32 MiB guaranteed by round-4 pass).
// ---------------------------------------------------------------------------

typedef __attribute__((ext_vector_type(8))) short short8;   // 8 bf16 = 4 VGPR
typedef __attribute__((ext_vector_type(4))) float floatx4;  // MFMA acc

__device__ __forceinline__ float b2f(short s) {
  union { unsigned u; float f; } v;
  v.u = ((unsigned)(unsigned short)s) << 16;
  return v.f;
}
__device__ __forceinline__ short f2b(float f) {
  union { float f; unsigned u; } v;
  v.f = f;
  unsigned r = v.u + 0x7FFFu + ((v.u >> 16) & 1u);  // RNE
  return (short)(r >> 16);
}
__device__ __forceinline__ float fast_tanh(float x) {
  float e = __expf(2.f * x);
  return 1.f - 2.f / (e + 1.f);
}
__device__ __forceinline__ void load16_lds(const void* g, void* l) {
  __builtin_amdgcn_global_load_lds(
      (__attribute__((address_space(1))) void*)(void*)g,
      (__attribute__((address_space(3))) void*)l, 16, 0, 0);
}

// ---------------------------------------------------------------------------
// fp32 -> bf16 conversion, 8 elems/thread.
// ---------------------------------------------------------------------------
__global__ __launch_bounds__(256) void cvt_kernel(const float* __restrict__ x,
                                                  short* __restrict__ y,
                                                  int n8) {
  const int i = blockIdx.x * 256 + threadIdx.x;
  if (i >= n8) return;
  const float4 a = ((const float4*)x)[(size_t)i * 2];
  const float4 b = ((const float4*)x)[(size_t)i * 2 + 1];
  short8 r;
  r[0] = f2b(a.x); r[1] = f2b(a.y); r[2] = f2b(a.z); r[3] = f2b(a.w);
  r[4] = f2b(b.x); r[5] = f2b(b.y); r[6] = f2b(b.z); r[7] = f2b(b.w);
  ((short8*)y)[i] = r;
}

// ---------------------------------------------------------------------------
// GEMM: C[M,N] = A[M,K] @ W[N,K]^T  (bf16 in, fp32 acc).
// grid = (N/128, M/128, ZSEL?2:1), block = 256 (4 waves, 2x2 of 64x64).
// m97 staging: global_load_lds 16B/lane, unpadded LDS 128x64.
// EPI 0: store bf16
// EPI 1: c + aux_f32[r][n], store fp32
// EPI 2: tanh(c + bias[n]), store bf16
// EPI 3: tanh(c + bias[n]) + res_f32[r][n], store fp32 (res MAY ALIAS C)
// ZSEL: blockIdx.z==1 switches to Wz/biasz, A += a_zoff, C/res += c_zoff.
// ---------------------------------------------------------------------------
template <int EPI, int ZSEL>
__global__ __launch_bounds__(256) void gemm_bt(
    const short* A, int lda, const short* W, int K, void* Cout, int ldc,
    const float* aux, int ld_aux, const float* bias, const float* res, int ldr,
    const short* Wz, const float* biasz, int a_zoff, int c_zoff) {
  __shared__ short As[128 * 64];
  __shared__ short Bs[128 * 64];
  const int tid = threadIdx.x;
  const int lane = tid & 63;
  const int wid = tid >> 6;
  const int l15 = lane & 15;
  const int l4 = lane >> 4;
  const int wm = (wid >> 1) * 64;
  const int wn = (wid & 1) * 64;
  const int bn0 = blockIdx.x * 128;
  const int bm0 = blockIdx.y * 128;

  const short* Wp = W;
  const float* bp = bias;
  int coff = 0;
  if (ZSEL && blockIdx.z) {
    Wp = Wz;
    bp = biasz;
    A += a_zoff;
    coff = c_zoff;
  }

  floatx4 zero = {0.f, 0.f, 0.f, 0.f};
  floatx4 acc[4][4];
#pragma unroll
  for (int i = 0; i < 4; ++i)
#pragma unroll
    for (int j = 0; j < 4; ++j) acc[i][j] = zero;

  // staging: issue e covers rows e*8..e*8+7; lane -> row e*8+(lane>>3),
  // k-granule (lane&7)*8 shorts; LDS dest = e*1024B + lane*16B (row-major).
  const short* Abase = A + (size_t)(bm0 + (lane >> 3)) * lda + (lane & 7) * 8;
  const short* Wbase = Wp + (size_t)(bn0 + (lane >> 3)) * K + (lane & 7) * 8;

  for (int k0 = 0; k0 < K; k0 += 64) {
#pragma unroll
    for (int t = 0; t < 4; ++t) {
      const int e = wid * 4 + t;
      load16_lds(Abase + (size_t)e * 8 * lda + k0, &As[e * 512]);
      load16_lds(Wbase + (size_t)e * 8 * K + k0, &Bs[e * 512]);
    }
    __syncthreads();  // compiler drains vmcnt(0) before s_barrier
#pragma unroll
    for (int kk = 0; kk < 2; ++kk) {
      const int ko = (kk * 4 + l4) * 8;
      short8 av[4], bv[4];
#pragma unroll
      for (int i = 0; i < 4; ++i) {
        av[i] = *(const short8*)&As[(wm + i * 16 + l15) * 64 + ko];
        bv[i] = *(const short8*)&Bs[(wn + i * 16 + l15) * 64 + ko];
      }
#pragma unroll
      for (int i = 0; i < 4; ++i)
#pragma unroll
        for (int j = 0; j < 4; ++j)
          acc[i][j] = __builtin_amdgcn_mfma_f32_16x16x32_bf16(av[i], bv[j],
                                                              acc[i][j], 0, 0, 0);
    }
    __syncthreads();
  }

  // epilogue: lane holds C[mb + i*16 + p][nb + j*16], p = 0..3
  const int mb = bm0 + wm + l4 * 4;
  const int nb = bn0 + wn + l15;
#pragma unroll
  for (int i = 0; i < 4; ++i) {
#pragma unroll
    for (int p = 0; p < 4; ++p) {
      const int r = mb + i * 16 + p;
#pragma unroll
      for (int j = 0; j < 4; ++j) {
        const int n = nb + j * 16;
        float c = acc[i][j][p];
        if (EPI == 0) {
          ((short*)Cout)[(size_t)r * ldc + n + coff] = f2b(c);
        } else if (EPI == 1) {
          ((float*)Cout)[(size_t)r * ldc + n + coff] =
              c + aux[(size_t)r * ld_aux + n];
        } else if (EPI == 2) {
          ((short*)Cout)[(size_t)r * ldc + n + coff] =
              f2b(fast_tanh(c + bp[n]));
        } else {
          const float rv = res[(size_t)r * ldr + n + coff];  // load pre-store
          ((float*)Cout)[(size_t)r * ldc + n + coff] =
              fast_tanh(c + bp[n]) + rv;
        }
      }
    }
  }
}

// ---------------------------------------------------------------------------
// LayerNorm over (S,E) = 2048 fp32 elems per batch. One block per batch.
// fp32 in, bf16 out. w/b fp32 (length 2048).
// ---------------------------------------------------------------------------
__global__ __launch_bounds__(256) void ln_kernel(const float* __restrict__ x,
                                                 const float* __restrict__ w,
                                                 const float* __restrict__ bb,
                                                 short* __restrict__ y) {
  const int b = blockIdx.x;
  const int tid = threadIdx.x;
  const size_t base = (size_t)b * 2048 + tid * 8;
  float xv[8];
  {
    const float4 a = *(const float4*)(x + base);
    const float4 c = *(const float4*)(x + base + 4);
    xv[0] = a.x; xv[1] = a.y; xv[2] = a.z; xv[3] = a.w;
    xv[4] = c.x; xv[5] = c.y; xv[6] = c.z; xv[7] = c.w;
  }
  float sum = 0.f, sq = 0.f;
#pragma unroll
  for (int j = 0; j < 8; ++j) {
    sum += xv[j];
    sq += xv[j] * xv[j];
  }
  __shared__ float rs[8];
  const int lane = tid & 63, wid = tid >> 6;
#pragma unroll
  for (int off = 32; off; off >>= 1) {
    sum += __shfl_down(sum, off);
    sq += __shfl_down(sq, off);
  }
  if (lane == 0) {
    rs[wid] = sum;
    rs[4 + wid] = sq;
  }
  __syncthreads();
  const float stot = rs[0] + rs[1] + rs[2] + rs[3];
  const float qtot = rs[4] + rs[5] + rs[6] + rs[7];
  const float mean = stot * (1.f / 2048.f);
  const float rstd = rsqrtf(qtot * (1.f / 2048.f) - mean * mean + 1e-5f);
  const int wi = tid * 8;
  short8 r;
#pragma unroll
  for (int j = 0; j < 8; ++j)
    r[j] = f2b((xv[j] - mean) * rstd * w[wi + j] + bb[wi + j]);
  *(short8*)(y + base) = r;
}

// ---------------------------------------------------------------------------
// Attention, S=2, on the fused QKV buffer (row stride 3072: q|k|v columns).
// q[b,h,s,d] = qkv[b*2+s][d*16+h]; scores (2x2)/8; softmax over t;
// concat[b,s,e] = p0*v[b,0,e] + p1*v[b,1,e], h = e&15. Overwrites q cols.
// Block=256 handles 2 b's (128 threads each).
// ---------------------------------------------------------------------------
__global__ __launch_bounds__(256) void attn_kernel(short* qkv) {
  __shared__ short sm[2][6][1032];    // q0,q1,k0,k1,v0,v1
  __shared__ float sps[2][2][2][16];  // [half][s][t][h] scores
  __shared__ float spp[2][2][2][16];  // [half][s][t][h] probs
  const int tid = threadIdx.x;
  const int half = tid >> 7;
  const int t = tid & 127;
  const int b = blockIdx.x * 2 + half;
  const short* row0 = qkv + ((size_t)b * 2 + 0) * 3072;
  const short* row1 = qkv + ((size_t)b * 2 + 1) * 3072;
  const short* srcs[6] = {row0,        row1,        row0 + 1024,
                          row1 + 1024, row0 + 2048, row1 + 2048};
#pragma unroll
  for (int rr = 0; rr < 6; ++rr)
    *(short8*)&sm[half][rr][t * 8] = *(const short8*)(srcs[rr] + t * 8);
  __syncthreads();
  if (t < 64) {
    const int h = t & 15, comb = t >> 4;
    const int si = comb >> 1, ti = comb & 1;
    const short* qr = sm[half][si];
    const short* kr = sm[half][2 + ti];
    float a = 0.f;
#pragma unroll
    for (int d = 0; d < 64; ++d) a += b2f(qr[d * 16 + h]) * b2f(kr[d * 16 + h]);
    sps[half][si][ti][h] = a * 0.125f;  // / sqrt(NH=64)
  }
  __syncthreads();
  if (t < 32) {
    const int h = t & 15, si = t >> 4;
    const float s0 = sps[half][si][0][h], s1 = sps[half][si][1][h];
    const float m = fmaxf(s0, s1);
    const float e0 = __expf(s0 - m), e1 = __expf(s1 - m);
    const float inv = 1.f / (e0 + e1);
    spp[half][si][0][h] = e0 * inv;
    spp[half][si][1][h] = e1 * inv;
  }
  __syncthreads();
#pragma unroll
  for (int si = 0; si < 2; ++si) {
    short8 r;
#pragma unroll
    for (int j = 0; j < 8; ++j) {
      const int e = t * 8 + j;
      const int h = e & 15;
      const float c = spp[half][si][0][h] * b2f(sm[half][4][e]) +
                      spp[half][si][1][h] * b2f(sm[half][5][e]);
      r[j] = f2b(c);
    }
    *(short8*)(qkv + ((size_t)b * 2 + si) * 3072 + t * 8) = r;
  }
}

// ---------------------------------------------------------------------------
extern "C" void kernel_launch(void* const* d_in, const int* in_sizes, int n_in,
                              void* d_out, int out_size, void* d_ws,
                              size_t ws_size, hipStream_t stream) {
  (void)in_sizes; (void)n_in; (void)out_size;
  const float* input = (const float*)d_in[0];
  const float* Wq = (const float*)d_in[1];
  const float* Wk = (const float*)d_in[2];
  const float* Wv = (const float*)d_in[3];
  const float* Wo = (const float*)d_in[4];
  const float* ln1w = (const float*)d_in[5];
  const float* ln1b = (const float*)d_in[6];
  const float* ln2w = (const float*)d_in[7];
  const float* ln2b = (const float*)d_in[8];
  const float* f1w1 = (const float*)d_in[9];
  const float* f1b1 = (const float*)d_in[10];
  const float* f1w2 = (const float*)d_in[11];
  const float* f1b2 = (const float*)d_in[12];
  const float* f2w1 = (const float*)d_in[13];
  const float* f2b1 = (const float*)d_in[14];
  const float* f2w2 = (const float*)d_in[15];
  const float* f2b2 = (const float*)d_in[16];
  float* out = (float*)d_out;
  char* ws = (char*)d_ws;

  const size_t MB = 1024 * 1024;
  dim3 blk(256);

  // ---- Phase 1: LN1 -> fused QKV -> attn -> O-proj(+resid) ---------------
  // ws: wqkv [0,6MB) wo [6,8MB) | xs (rows x 1024 bf16) | qkv (rows x 3072)
  {
    short* wqkv = (short*)ws;
    short* wo = (short*)(ws + 6 * MB);
    cvt_kernel<<<512, blk, 0, stream>>>(Wq, wqkv, 131072);
    cvt_kernel<<<512, blk, 0, stream>>>(Wk, wqkv + 1024 * 1024, 131072);
    cvt_kernel<<<512, blk, 0, stream>>>(Wv, wqkv + 2 * 1024 * 1024, 131072);
    cvt_kernel<<<512, blk, 0, stream>>>(Wo, wo, 131072);
    // per-row bytes: xs 2048 + qkv 6144 = 8192
    size_t avail = ws_size - 8 * MB;
    int max_rows = (int)((avail / 8192) / 128) * 128;
    if (max_rows > 16384) max_rows = 16384;
    if (max_rows < 128) max_rows = 128;
    short* xs = (short*)(ws + 8 * MB);
    short* qkvb = xs + (size_t)max_rows * 1024;
    for (int r0 = 0; r0 < 16384; r0 += max_rows) {
      const int R = (16384 - r0 < max_rows) ? (16384 - r0) : max_rows;
      const float* inp_c = input + (size_t)r0 * 1024;
      float* out_c = out + (size_t)r0 * 1024;
      ln_kernel<<<R / 2, blk, 0, stream>>>(inp_c, ln1w, ln1b, xs);
      dim3 gqkv(24, R / 128);
      gemm_bt<0, 0><<<gqkv, blk, 0, stream>>>(
          xs, 1024, wqkv, 1024, qkvb, 3072, nullptr, 0, nullptr, nullptr, 0,
          nullptr, nullptr, 0, 0);
      attn_kernel<<<R / 4, blk, 0, stream>>>(qkvb);
      dim3 go(8, R / 128);
      gemm_bt<1, 0><<<go, blk, 0, stream>>>(
          qkvb, 3072, wo, 1024, out_c, 1024, inp_c, 1024, nullptr, nullptr, 0,
          nullptr, nullptr, 0, 0);
    }
  }

  // ---- Phase 2: LN2 -> FFN1(z=s) -> FFN2(z=s, +resid RMW on d_out) -------
  // ws: fw1[2] [0,8MB) fw2[2] [8,16MB) | outs (b x 2048) | hb (b x 4096)
  {
    short* fw1s0 = (short*)ws;
    short* fw1s1 = (short*)(ws + 4 * MB);
    short* fw2s0 = (short*)(ws + 8 * MB);
    short* fw2s1 = (short*)(ws + 12 * MB);
    cvt_kernel<<<1024, blk, 0, stream>>>(f1w1, fw1s0, 262144);
    cvt_kernel<<<1024, blk, 0, stream>>>(f2w1, fw1s1, 262144);
    cvt_kernel<<<1024, blk, 0, stream>>>(f1w2, fw2s0, 262144);
    cvt_kernel<<<1024, blk, 0, stream>>>(f2w2, fw2s1, 262144);
    // per-batch bytes: outs 4096 + hb 8192 = 12288
    size_t avail = ws_size - 16 * MB;
    int max_b = (int)((avail / 12288) / 128) * 128;
    if (max_b > 8192) max_b = 8192;
    if (max_b < 128) max_b = 128;
    short* outs = (short*)(ws + 16 * MB);
    short* hb = outs + (size_t)max_b * 2048;
    for (int b0 = 0; b0 < 8192; b0 += max_b) {
      const int BB = (8192 - b0 < max_b) ? (8192 - b0) : max_b;
      float* out_c = out + (size_t)b0 * 2048;
      ln_kernel<<<BB, blk, 0, stream>>>(out_c, ln2w, ln2b, outs);
      // h_s = tanh(outs_s @ w1_s^T + b1_s): M=BB, N=2048, K=1024, z=s
      dim3 g1(16, BB / 128, 2);
      gemm_bt<2, 1><<<g1, blk, 0, stream>>>(
          outs, 2048, fw1s0, 1024, hb, 4096, nullptr, 0, f1b1, nullptr, 0,
          fw1s1, f2b1, /*a_zoff=*/1024, /*c_zoff=*/2048);
      // out_s = tanh(h_s @ w2_s^T + b2_s) + out1_s: M=BB, N=1024, K=2048
      dim3 g2(8, BB / 128, 2);
      gemm_bt<3, 1><<<g2, blk, 0, stream>>>(
          hb, 4096, fw2s0, 2048, out_c, 2048, nullptr, 0, f1b2, out_c, 2048,
          fw2s1, f2b2, /*a_zoff=*/2048, /*c_zoff=*/1024);
    }
  }
}

// Round 6
// 621.294 us; speedup vs baseline: 2.1176x; 1.1241x over previous
//
#include <hip/hip_runtime.h>
#include <hip/hip_bf16.h>
#include <stdint.h>

// ---------------------------------------------------------------------------
// InterFusion, fp32 I/O: LN1 -> QKV(fused N=3072) -> attn(S=2) ->
// O-proj(+resid -> out1 bf16 in ws) -> LN2 -> FFN1 -> FFN2(+resid -> fp32 out).
// bf16 MFMA 16x16x32, fp32 acc; global_load_lds(16B) staging with XOR-swizzled
// LDS k-granules (bank-conflict floor). ws >= 136 MiB (proven round 5).
// ---------------------------------------------------------------------------

typedef __attribute__((ext_vector_type(8))) short short8;   // 8 bf16 = 4 VGPR
typedef __attribute__((ext_vector_type(4))) float floatx4;  // MFMA acc

__device__ __forceinline__ float b2f(short s) {
  union { unsigned u; float f; } v;
  v.u = ((unsigned)(unsigned short)s) << 16;
  return v.f;
}
__device__ __forceinline__ short f2b(float f) {
  union { float f; unsigned u; } v;
  v.f = f;
  unsigned r = v.u + 0x7FFFu + ((v.u >> 16) & 1u);  // RNE
  return (short)(r >> 16);
}
__device__ __forceinline__ float fast_tanh(float x) {
  float e = __expf(2.f * x);
  return 1.f - 2.f / (e + 1.f);
}
__device__ __forceinline__ void load16_lds(const void* g, void* l) {
  __builtin_amdgcn_global_load_lds(
      (__attribute__((address_space(1))) void*)(void*)g,
      (__attribute__((address_space(3))) void*)l, 16, 0, 0);
}

// ---------------------------------------------------------------------------
// 4-source fp32 -> bf16 conversion into one contiguous bf16 region.
// per-source element count = 8 << sh; one thread converts 8 elems.
// ---------------------------------------------------------------------------
struct Src4 { const float* p[4]; };

__global__ __launch_bounds__(256) void cvt4_kernel(Src4 s,
                                                   short* __restrict__ y,
                                                   int sh) {
  const int i = blockIdx.x * 256 + threadIdx.x;  // global 8-elem index
  const int seg = i >> sh;
  const int off = i & ((1 << sh) - 1);
  const float* x = s.p[seg];
  const float4 a = ((const float4*)x)[(size_t)off * 2];
  const float4 b = ((const float4*)x)[(size_t)off * 2 + 1];
  short8 r;
  r[0] = f2b(a.x); r[1] = f2b(a.y); r[2] = f2b(a.z); r[3] = f2b(a.w);
  r[4] = f2b(b.x); r[5] = f2b(b.y); r[6] = f2b(b.z); r[7] = f2b(b.w);
  ((short8*)y)[i] = r;
}

// ---------------------------------------------------------------------------
// GEMM: C[M,N] = A[M,K] @ W[N,K]^T  (bf16 in, fp32 acc).
// grid = (N/128, M/128, ZSEL?2:1), block = 256 (4 waves, 2x2 of 64x64).
// Staging: global_load_lds 16B/lane; lane loads k-granule (lane&7)^(row&7),
// so LDS slot c of row r holds granule c^(r&7); reads use ko=(gk^(r&7))*8.
// EPI 0: store bf16
// EPI 1: c + aux_f32[r][n], store bf16            (out1 = Oproj + input)
// EPI 2: tanh(c + bias[n]), store bf16            (FFN hidden)
// EPI 3: tanh(c + bias[n]) + b2f(res_bf16), store fp32   (final output)
// ZSEL: blockIdx.z==1 -> Wz/biasz, A += a_zoff, C/res += c_zoff.
// ---------------------------------------------------------------------------
template <int EPI, int ZSEL>
__global__ __launch_bounds__(256) void gemm_bt(
    const short* A, int lda, const short* W, int K, void* Cout, int ldc,
    const float* aux, int ld_aux, const float* bias, const short* res, int ldr,
    const short* Wz, const float* biasz, int a_zoff, int c_zoff) {
  __shared__ short As[128 * 64];
  __shared__ short Bs[128 * 64];
  const int tid = threadIdx.x;
  const int lane = tid & 63;
  const int wid = tid >> 6;
  const int l15 = lane & 15;
  const int l4 = lane >> 4;
  const int wm = (wid >> 1) * 64;
  const int wn = (wid & 1) * 64;
  const int bn0 = blockIdx.x * 128;
  const int bm0 = blockIdx.y * 128;

  const short* Wp = W;
  const float* bp = bias;
  int coff = 0;
  if (ZSEL && blockIdx.z) {
    Wp = Wz;
    bp = biasz;
    A += a_zoff;
    coff = c_zoff;
  }

  floatx4 zero = {0.f, 0.f, 0.f, 0.f};
  floatx4 acc[4][4];
#pragma unroll
  for (int i = 0; i < 4; ++i)
#pragma unroll
    for (int j = 0; j < 4; ++j) acc[i][j] = zero;

  // staging: issue e covers rows e*8..e*8+7; lane -> row e*8+r8, loads
  // granule (lane&7)^r8; lands at LDS slot (lane&7) of that row.
  const int r8 = lane >> 3;
  const int gsw = (lane & 7) ^ r8;
  const short* Abase = A + (size_t)(bm0 + r8) * lda + gsw * 8;
  const short* Wbase = Wp + (size_t)(bn0 + r8) * K + gsw * 8;
  const int swz = l15 & 7;  // read-side swizzle key (= fragment row & 7)

  for (int k0 = 0; k0 < K; k0 += 64) {
#pragma unroll
    for (int t = 0; t < 4; ++t) {
      const int e = wid * 4 + t;
      load16_lds(Abase + (size_t)e * 8 * lda + k0, &As[e * 512]);
      load16_lds(Wbase + (size_t)e * 8 * K + k0, &Bs[e * 512]);
    }
    __syncthreads();  // compiler drains vmcnt(0) before s_barrier
#pragma unroll
    for (int kk = 0; kk < 2; ++kk) {
      const int ko = ((kk * 4 + l4) ^ swz) * 8;
      short8 av[4], bv[4];
#pragma unroll
      for (int i = 0; i < 4; ++i) {
        av[i] = *(const short8*)&As[(wm + i * 16 + l15) * 64 + ko];
        bv[i] = *(const short8*)&Bs[(wn + i * 16 + l15) * 64 + ko];
      }
#pragma unroll
      for (int i = 0; i < 4; ++i)
#pragma unroll
        for (int j = 0; j < 4; ++j)
          acc[i][j] = __builtin_amdgcn_mfma_f32_16x16x32_bf16(av[i], bv[j],
                                                              acc[i][j], 0, 0, 0);
    }
    __syncthreads();
  }

  // epilogue: lane holds C[mb + i*16 + p][nb + j*16], p = 0..3
  const int mb = bm0 + wm + l4 * 4;
  const int nb = bn0 + wn + l15;
#pragma unroll
  for (int i = 0; i < 4; ++i) {
#pragma unroll
    for (int p = 0; p < 4; ++p) {
      const int r = mb + i * 16 + p;
#pragma unroll
      for (int j = 0; j < 4; ++j) {
        const int n = nb + j * 16;
        float c = acc[i][j][p];
        if (EPI == 0) {
          ((short*)Cout)[(size_t)r * ldc + n + coff] = f2b(c);
        } else if (EPI == 1) {
          ((short*)Cout)[(size_t)r * ldc + n + coff] =
              f2b(c + aux[(size_t)r * ld_aux + n]);
        } else if (EPI == 2) {
          ((short*)Cout)[(size_t)r * ldc + n + coff] =
              f2b(fast_tanh(c + bp[n]));
        } else {
          const float rv = b2f(res[(size_t)r * ldr + n + coff]);
          ((float*)Cout)[(size_t)r * ldc + n + coff] =
              fast_tanh(c + bp[n]) + rv;
        }
      }
    }
  }
}

// ---------------------------------------------------------------------------
// LayerNorm over (S,E) = 2048 elems per batch. One block per batch.
// INBF16 selects input dtype; output bf16. w/b fp32 (length 2048).
// ---------------------------------------------------------------------------
template <int INBF16>
__global__ __launch_bounds__(256) void ln_kernel(const void* __restrict__ xin,
                                                 const float* __restrict__ w,
                                                 const float* __restrict__ bb,
                                                 short* __restrict__ y) {
  const int b = blockIdx.x;
  const int tid = threadIdx.x;
  const size_t base = (size_t)b * 2048 + tid * 8;
  float xv[8];
  if (INBF16) {
    short8 s = *(const short8*)((const short*)xin + base);
#pragma unroll
    for (int j = 0; j < 8; ++j) xv[j] = b2f(s[j]);
  } else {
    const float4 a = *(const float4*)((const float*)xin + base);
    const float4 c = *(const float4*)((const float*)xin + base + 4);
    xv[0] = a.x; xv[1] = a.y; xv[2] = a.z; xv[3] = a.w;
    xv[4] = c.x; xv[5] = c.y; xv[6] = c.z; xv[7] = c.w;
  }
  float sum = 0.f, sq = 0.f;
#pragma unroll
  for (int j = 0; j < 8; ++j) {
    sum += xv[j];
    sq += xv[j] * xv[j];
  }
  __shared__ float rs[8];
  const int lane = tid & 63, wid = tid >> 6;
#pragma unroll
  for (int off = 32; off; off >>= 1) {
    sum += __shfl_down(sum, off);
    sq += __shfl_down(sq, off);
  }
  if (lane == 0) {
    rs[wid] = sum;
    rs[4 + wid] = sq;
  }
  __syncthreads();
  const float stot = rs[0] + rs[1] + rs[2] + rs[3];
  const float qtot = rs[4] + rs[5] + rs[6] + rs[7];
  const float mean = stot * (1.f / 2048.f);
  const float rstd = rsqrtf(qtot * (1.f / 2048.f) - mean * mean + 1e-5f);
  const int wi = tid * 8;
  short8 r;
#pragma unroll
  for (int j = 0; j < 8; ++j)
    r[j] = f2b((xv[j] - mean) * rstd * w[wi + j] + bb[wi + j]);
  *(short8*)(y + base) = r;
}

// ---------------------------------------------------------------------------
// Attention, S=2, on the fused QKV buffer (row stride 3072: q|k|v columns).
// q[b,h,s,d] = qkv[b*2+s][d*16+h]; scores (2x2)/8; softmax over t;
// concat[b,s,e] = p0*v[b,0,e] + p1*v[b,1,e], h = e&15. Overwrites q cols.
// Block=256 handles 2 b's (128 threads each).
// ---------------------------------------------------------------------------
__global__ __launch_bounds__(256) void attn_kernel(short* qkv) {
  __shared__ short sm[2][6][1032];    // q0,q1,k0,k1,v0,v1
  __shared__ float sps[2][2][2][16];  // [half][s][t][h] scores
  __shared__ float spp[2][2][2][16];  // [half][s][t][h] probs
  const int tid = threadIdx.x;
  const int half = tid >> 7;
  const int t = tid & 127;
  const int b = blockIdx.x * 2 + half;
  const short* row0 = qkv + ((size_t)b * 2 + 0) * 3072;
  const short* row1 = qkv + ((size_t)b * 2 + 1) * 3072;
  const short* srcs[6] = {row0,        row1,        row0 + 1024,
                          row1 + 1024, row0 + 2048, row1 + 2048};
#pragma unroll
  for (int rr = 0; rr < 6; ++rr)
    *(short8*)&sm[half][rr][t * 8] = *(const short8*)(srcs[rr] + t * 8);
  __syncthreads();
  if (t < 64) {
    const int h = t & 15, comb = t >> 4;
    const int si = comb >> 1, ti = comb & 1;
    const short* qr = sm[half][si];
    const short* kr = sm[half][2 + ti];
    float a = 0.f;
#pragma unroll
    for (int d = 0; d < 64; ++d) a += b2f(qr[d * 16 + h]) * b2f(kr[d * 16 + h]);
    sps[half][si][ti][h] = a * 0.125f;  // / sqrt(NH=64)
  }
  __syncthreads();
  if (t < 32) {
    const int h = t & 15, si = t >> 4;
    const float s0 = sps[half][si][0][h], s1 = sps[half][si][1][h];
    const float m = fmaxf(s0, s1);
    const float e0 = __expf(s0 - m), e1 = __expf(s1 - m);
    const float inv = 1.f / (e0 + e1);
    spp[half][si][0][h] = e0 * inv;
    spp[half][si][1][h] = e1 * inv;
  }
  __syncthreads();
#pragma unroll
  for (int si = 0; si < 2; ++si) {
    short8 r;
#pragma unroll
    for (int j = 0; j < 8; ++j) {
      const int e = t * 8 + j;
      const int h = e & 15;
      const float c = spp[half][si][0][h] * b2f(sm[half][4][e]) +
                      spp[half][si][1][h] * b2f(sm[half][5][e]);
      r[j] = f2b(c);
    }
    *(short8*)(qkv + ((size_t)b * 2 + si) * 3072 + t * 8) = r;
  }
}

// ---------------------------------------------------------------------------
extern "C" void kernel_launch(void* const* d_in, const int* in_sizes, int n_in,
                              void* d_out, int out_size, void* d_ws,
                              size_t ws_size, hipStream_t stream) {
  (void)in_sizes; (void)n_in; (void)out_size; (void)ws_size;
  const float* input = (const float*)d_in[0];
  const float* Wq = (const float*)d_in[1];
  const float* Wk = (const float*)d_in[2];
  const float* Wv = (const float*)d_in[3];
  const float* Wo = (const float*)d_in[4];
  const float* ln1w = (const float*)d_in[5];
  const float* ln1b = (const float*)d_in[6];
  const float* ln2w = (const float*)d_in[7];
  const float* ln2b = (const float*)d_in[8];
  const float* f1w1 = (const float*)d_in[9];
  const float* f1b1 = (const float*)d_in[10];
  const float* f1w2 = (const float*)d_in[11];
  const float* f1b2 = (const float*)d_in[12];
  const float* f2w1 = (const float*)d_in[13];
  const float* f2b1 = (const float*)d_in[14];
  const float* f2w2 = (const float*)d_in[15];
  const float* f2b2 = (const float*)d_in[16];
  float* out = (float*)d_out;
  char* ws = (char*)d_ws;

  const size_t MB = 1024 * 1024;
  dim3 blk(256);

  // ws layout (peak 136 MiB, proven available by round-5 unchunked run):
  //   wqkv   [0,6)    wo [6,8)                      (phase-1 weights, bf16)
  //   xs     [8,40)   -> out1 (bf16) after QKV      (16384 x 1024)
  //   qkv    [40,136)                               (16384 x 3072)
  //   phase 2: fw [40,56), outs [56,72), hb [72,104); out1 persists [8,40)
  short* wqkv = (short*)ws;
  short* wo = (short*)(ws + 6 * MB);
  short* xs = (short*)(ws + 8 * MB);
  short* out1 = xs;  // overwrites xs (dead after QKV GEMM)
  short* qkvb = (short*)(ws + 40 * MB);

  // ---- Phase 1 -----------------------------------------------------------
  {
    Src4 s{{Wq, Wk, Wv, Wo}};
    cvt4_kernel<<<2048, blk, 0, stream>>>(s, wqkv, 17);  // 4 x 1M elems
  }
  ln_kernel<0><<<8192, blk, 0, stream>>>(input, ln1w, ln1b, xs);
  {
    dim3 g(24, 128);
    gemm_bt<0, 0><<<g, blk, 0, stream>>>(xs, 1024, wqkv, 1024, qkvb, 3072,
                                         nullptr, 0, nullptr, nullptr, 0,
                                         nullptr, nullptr, 0, 0);
  }
  attn_kernel<<<4096, blk, 0, stream>>>(qkvb);
  {
    dim3 g(8, 128);
    // out1 = concat @ Wo^T + input  -> bf16 (overwrites xs)
    gemm_bt<1, 0><<<g, blk, 0, stream>>>(qkvb, 3072, wo, 1024, out1, 1024,
                                         input, 1024, nullptr, nullptr, 0,
                                         nullptr, nullptr, 0, 0);
  }

  // ---- Phase 2 -----------------------------------------------------------
  short* fw1s0 = (short*)(ws + 40 * MB);
  short* fw1s1 = (short*)(ws + 44 * MB);
  short* fw2s0 = (short*)(ws + 48 * MB);
  short* fw2s1 = (short*)(ws + 52 * MB);
  short* outs = (short*)(ws + 56 * MB);  // 4096 x 2048 bf16 per chunk
  short* hb = (short*)(ws + 72 * MB);    // 4096 x 4096 bf16 per chunk
  {
    Src4 s{{f1w1, f2w1, f1w2, f2w2}};
    cvt4_kernel<<<4096, blk, 0, stream>>>(s, fw1s0, 18);  // 4 x 2M elems
  }
  const int CH = 4096;  // batches per chunk
  for (int b0 = 0; b0 < 8192; b0 += CH) {
    short* out1_c = out1 + (size_t)b0 * 2048;
    float* out_c = out + (size_t)b0 * 2048;
    ln_kernel<1><<<CH, blk, 0, stream>>>(out1_c, ln2w, ln2b, outs);
    // h_s = tanh(outs_s @ w1_s^T + b1_s): M=CH, N=2048, K=1024, z=s
    dim3 g1(16, CH / 128, 2);
    gemm_bt<2, 1><<<g1, blk, 0, stream>>>(
        outs, 2048, fw1s0, 1024, hb, 4096, nullptr, 0, f1b1, nullptr, 0,
        fw1s1, f2b1, /*a_zoff=*/1024, /*c_zoff=*/2048);
    // out_s = tanh(h_s @ w2_s^T + b2_s) + out1_s  (fp32 -> d_out)
    dim3 g2(8, CH / 128, 2);
    gemm_bt<3, 1><<<g2, blk, 0, stream>>>(
        hb, 4096, fw2s0, 2048, out_c, 2048, nullptr, 0, f1b2, out1_c, 2048,
        fw2s1, f2b2, /*a_zoff=*/2048, /*c_zoff=*/1024);
  }
}

// Round 7
// 570.449 us; speedup vs baseline: 2.3064x; 1.0891x over previous
//
#include <hip/hip_runtime.h>
#include <hip/hip_bf16.h>
#include <stdint.h>

// ---------------------------------------------------------------------------
// InterFusion, fp32 I/O: LN1 -> QKV(fused N=3072) -> attn(S=2) ->
// O-proj(+resid -> out1 bf16 in ws) -> LN2 -> FFN1 -> FFN2(+resid -> fp32 out).
// bf16 MFMA 16x16x32, fp32 acc; global_load_lds(16B) staging, XOR-swizzled
// LDS (0 bank conflicts, round 6). This round: SGPR-based staging addressing
// + __launch_bounds__(256,4) -> 128 regs -> 4 blocks/CU (was 3).
// ---------------------------------------------------------------------------

typedef __attribute__((ext_vector_type(8))) short short8;   // 8 bf16 = 4 VGPR
typedef __attribute__((ext_vector_type(4))) float floatx4;  // MFMA acc

__device__ __forceinline__ float b2f(short s) {
  union { unsigned u; float f; } v;
  v.u = ((unsigned)(unsigned short)s) << 16;
  return v.f;
}
__device__ __forceinline__ short f2b(float f) {
  union { float f; unsigned u; } v;
  v.f = f;
  unsigned r = v.u + 0x7FFFu + ((v.u >> 16) & 1u);  // RNE
  return (short)(r >> 16);
}
__device__ __forceinline__ float fast_tanh(float x) {
  float e = __expf(2.f * x);
  return 1.f - 2.f / (e + 1.f);
}
__device__ __forceinline__ void load16_lds(const void* g, void* l) {
  __builtin_amdgcn_global_load_lds(
      (__attribute__((address_space(1))) void*)(void*)g,
      (__attribute__((address_space(3))) void*)l, 16, 0, 0);
}

// ---------------------------------------------------------------------------
// 4-source fp32 -> bf16 conversion into one contiguous bf16 region.
// per-source element count = 8 << sh; one thread converts 8 elems.
// ---------------------------------------------------------------------------
struct Src4 { const float* p[4]; };

__global__ __launch_bounds__(256) void cvt4_kernel(Src4 s,
                                                   short* __restrict__ y,
                                                   int sh) {
  const int i = blockIdx.x * 256 + threadIdx.x;  // global 8-elem index
  const int seg = i >> sh;
  const int off = i & ((1 << sh) - 1);
  const float* x = s.p[seg];
  const float4 a = ((const float4*)x)[(size_t)off * 2];
  const float4 b = ((const float4*)x)[(size_t)off * 2 + 1];
  short8 r;
  r[0] = f2b(a.x); r[1] = f2b(a.y); r[2] = f2b(a.z); r[3] = f2b(a.w);
  r[4] = f2b(b.x); r[5] = f2b(b.y); r[6] = f2b(b.z); r[7] = f2b(b.w);
  ((short8*)y)[i] = r;
}

// ---------------------------------------------------------------------------
// GEMM: C[M,N] = A[M,K] @ W[N,K]^T  (bf16 in, fp32 acc).
// grid = (N/128, M/128, ZSEL?2:1), block = 256 (4 waves, 2x2 of 64x64).
// Staging: global_load_lds 16B/lane; lane loads k-granule (lane&7)^(row&7);
// reads use ko=(gk^(row&7))*8. Addressing: wave-uniform SGPR base per issue
// + one per-lane 32-bit offset (keeps VGPRs <= 64 for 4 blocks/CU).
// EPI 0: store bf16
// EPI 1: c + aux_f32[r][n], store bf16            (out1 = Oproj + input)
// EPI 2: tanh(c + bias[n]), store bf16            (FFN hidden)
// EPI 3: tanh(c + bias[n]) + b2f(res_bf16), store fp32   (final output)
// ZSEL: blockIdx.z==1 -> Wz/biasz, A += a_zoff, C/res += c_zoff.
// ---------------------------------------------------------------------------
template <int EPI, int ZSEL>
__global__ __launch_bounds__(256, 4) void gemm_bt(
    const short* A, int lda, const short* W, int K, void* Cout, int ldc,
    const float* aux, int ld_aux, const float* bias, const short* res, int ldr,
    const short* Wz, const float* biasz, int a_zoff, int c_zoff) {
  __shared__ short As[128 * 64];
  __shared__ short Bs[128 * 64];
  const int tid = threadIdx.x;
  const int lane = tid & 63;
  const int wid = tid >> 6;
  const int l15 = lane & 15;
  const int l4 = lane >> 4;
  const int wm = (wid >> 1) * 64;
  const int wn = (wid & 1) * 64;
  const int bn0 = blockIdx.x * 128;
  const int bm0 = blockIdx.y * 128;

  const short* Wp = W;
  const float* bp = bias;
  int coff = 0;
  if (ZSEL && blockIdx.z) {
    Wp = Wz;
    bp = biasz;
    A += a_zoff;
    coff = c_zoff;
  }

  floatx4 zero = {0.f, 0.f, 0.f, 0.f};
  floatx4 acc[4][4];
#pragma unroll
  for (int i = 0; i < 4; ++i)
#pragma unroll
    for (int j = 0; j < 4; ++j) acc[i][j] = zero;

  // staging: issue e covers rows e*8..e*8+7; lane -> row e*8+r8, loads
  // granule (lane&7)^r8 -> lands at LDS slot (lane&7) of its row.
  const int r8 = lane >> 3;
  const int gsw = (lane & 7) ^ r8;
  const int aoff = r8 * lda + gsw * 8;  // per-lane element offset (VGPR)
  const int boff = r8 * K + gsw * 8;
  const short* Ab = A + (size_t)bm0 * lda;    // wave-uniform
  const short* Bb = Wp + (size_t)bn0 * K;     // wave-uniform
  const int e0 = __builtin_amdgcn_readfirstlane(wid * 4);
  const int swz = l15 & 7;  // read-side swizzle key (= fragment row & 7)

  for (int k0 = 0; k0 < K; k0 += 64) {
#pragma unroll
    for (int t = 0; t < 4; ++t) {
      const int e = e0 + t;
      // uniform part: Ab + e*8*lda + k0 (SGPR); lane part: aoff (VGPR)
      load16_lds(Ab + (size_t)e * 8 * lda + k0 + aoff, &As[e * 512]);
      load16_lds(Bb + (size_t)e * 8 * K + k0 + boff, &Bs[e * 512]);
    }
    __syncthreads();  // compiler drains vmcnt(0) before s_barrier
#pragma unroll
    for (int kk = 0; kk < 2; ++kk) {
      const int ko = ((kk * 4 + l4) ^ swz) * 8;
      short8 av[4], bv[4];
#pragma unroll
      for (int i = 0; i < 4; ++i) {
        av[i] = *(const short8*)&As[(wm + i * 16 + l15) * 64 + ko];
        bv[i] = *(const short8*)&Bs[(wn + i * 16 + l15) * 64 + ko];
      }
#pragma unroll
      for (int i = 0; i < 4; ++i)
#pragma unroll
        for (int j = 0; j < 4; ++j)
          acc[i][j] = __builtin_amdgcn_mfma_f32_16x16x32_bf16(av[i], bv[j],
                                                              acc[i][j], 0, 0, 0);
    }
    __syncthreads();
  }

  // epilogue: lane holds C[mb + i*16 + p][nb + j*16], p = 0..3
  const int mb = bm0 + wm + l4 * 4;
  const int nb = bn0 + wn + l15;
#pragma unroll
  for (int i = 0; i < 4; ++i) {
#pragma unroll
    for (int p = 0; p < 4; ++p) {
      const int r = mb + i * 16 + p;
#pragma unroll
      for (int j = 0; j < 4; ++j) {
        const int n = nb + j * 16;
        float c = acc[i][j][p];
        if (EPI == 0) {
          ((short*)Cout)[(size_t)r * ldc + n + coff] = f2b(c);
        } else if (EPI == 1) {
          ((short*)Cout)[(size_t)r * ldc + n + coff] =
              f2b(c + aux[(size_t)r * ld_aux + n]);
        } else if (EPI == 2) {
          ((short*)Cout)[(size_t)r * ldc + n + coff] =
              f2b(fast_tanh(c + bp[n]));
        } else {
          const float rv = b2f(res[(size_t)r * ldr + n + coff]);
          ((float*)Cout)[(size_t)r * ldc + n + coff] =
              fast_tanh(c + bp[n]) + rv;
        }
      }
    }
  }
}

// ---------------------------------------------------------------------------
// LayerNorm over (S,E) = 2048 elems per batch. One block per batch.
// INBF16 selects input dtype; output bf16. w/b fp32 (length 2048).
// ---------------------------------------------------------------------------
template <int INBF16>
__global__ __launch_bounds__(256) void ln_kernel(const void* __restrict__ xin,
                                                 const float* __restrict__ w,
                                                 const float* __restrict__ bb,
                                                 short* __restrict__ y) {
  const int b = blockIdx.x;
  const int tid = threadIdx.x;
  const size_t base = (size_t)b * 2048 + tid * 8;
  float xv[8];
  if (INBF16) {
    short8 s = *(const short8*)((const short*)xin + base);
#pragma unroll
    for (int j = 0; j < 8; ++j) xv[j] = b2f(s[j]);
  } else {
    const float4 a = *(const float4*)((const float*)xin + base);
    const float4 c = *(const float4*)((const float*)xin + base + 4);
    xv[0] = a.x; xv[1] = a.y; xv[2] = a.z; xv[3] = a.w;
    xv[4] = c.x; xv[5] = c.y; xv[6] = c.z; xv[7] = c.w;
  }
  float sum = 0.f, sq = 0.f;
#pragma unroll
  for (int j = 0; j < 8; ++j) {
    sum += xv[j];
    sq += xv[j] * xv[j];
  }
  __shared__ float rs[8];
  const int lane = tid & 63, wid = tid >> 6;
#pragma unroll
  for (int off = 32; off; off >>= 1) {
    sum += __shfl_down(sum, off);
    sq += __shfl_down(sq, off);
  }
  if (lane == 0) {
    rs[wid] = sum;
    rs[4 + wid] = sq;
  }
  __syncthreads();
  const float stot = rs[0] + rs[1] + rs[2] + rs[3];
  const float qtot = rs[4] + rs[5] + rs[6] + rs[7];
  const float mean = stot * (1.f / 2048.f);
  const float rstd = rsqrtf(qtot * (1.f / 2048.f) - mean * mean + 1e-5f);
  const int wi = tid * 8;
  short8 r;
#pragma unroll
  for (int j = 0; j < 8; ++j)
    r[j] = f2b((xv[j] - mean) * rstd * w[wi + j] + bb[wi + j]);
  *(short8*)(y + base) = r;
}

// ---------------------------------------------------------------------------
// Attention, S=2, on the fused QKV buffer (row stride 3072: q|k|v columns).
// q[b,h,s,d] = qkv[b*2+s][d*16+h]; scores (2x2)/8; softmax over t;
// concat[b,s,e] = p0*v[b,0,e] + p1*v[b,1,e], h = e&15. Overwrites q cols.
// Block=256 handles 2 b's (128 threads each).
// ---------------------------------------------------------------------------
__global__ __launch_bounds__(256) void attn_kernel(short* qkv) {
  __shared__ short sm[2][6][1032];    // q0,q1,k0,k1,v0,v1
  __shared__ float sps[2][2][2][16];  // [half][s][t][h] scores
  __shared__ float spp[2][2][2][16];  // [half][s][t][h] probs
  const int tid = threadIdx.x;
  const int half = tid >> 7;
  const int t = tid & 127;
  const int b = blockIdx.x * 2 + half;
  const short* row0 = qkv + ((size_t)b * 2 + 0) * 3072;
  const short* row1 = qkv + ((size_t)b * 2 + 1) * 3072;
  const short* srcs[6] = {row0,        row1,        row0 + 1024,
                          row1 + 1024, row0 + 2048, row1 + 2048};
#pragma unroll
  for (int rr = 0; rr < 6; ++rr)
    *(short8*)&sm[half][rr][t * 8] = *(const short8*)(srcs[rr] + t * 8);
  __syncthreads();
  if (t < 64) {
    const int h = t & 15, comb = t >> 4;
    const int si = comb >> 1, ti = comb & 1;
    const short* qr = sm[half][si];
    const short* kr = sm[half][2 + ti];
    float a = 0.f;
#pragma unroll
    for (int d = 0; d < 64; ++d) a += b2f(qr[d * 16 + h]) * b2f(kr[d * 16 + h]);
    sps[half][si][ti][h] = a * 0.125f;  // / sqrt(NH=64)
  }
  __syncthreads();
  if (t < 32) {
    const int h = t & 15, si = t >> 4;
    const float s0 = sps[half][si][0][h], s1 = sps[half][si][1][h];
    const float m = fmaxf(s0, s1);
    const float e0 = __expf(s0 - m), e1 = __expf(s1 - m);
    const float inv = 1.f / (e0 + e1);
    spp[half][si][0][h] = e0 * inv;
    spp[half][si][1][h] = e1 * inv;
  }
  __syncthreads();
#pragma unroll
  for (int si = 0; si < 2; ++si) {
    short8 r;
#pragma unroll
    for (int j = 0; j < 8; ++j) {
      const int e = t * 8 + j;
      const int h = e & 15;
      const float c = spp[half][si][0][h] * b2f(sm[half][4][e]) +
                      spp[half][si][1][h] * b2f(sm[half][5][e]);
      r[j] = f2b(c);
    }
    *(short8*)(qkv + ((size_t)b * 2 + si) * 3072 + t * 8) = r;
  }
}

// ---------------------------------------------------------------------------
extern "C" void kernel_launch(void* const* d_in, const int* in_sizes, int n_in,
                              void* d_out, int out_size, void* d_ws,
                              size_t ws_size, hipStream_t stream) {
  (void)in_sizes; (void)n_in; (void)out_size; (void)ws_size;
  const float* input = (const float*)d_in[0];
  const float* Wq = (const float*)d_in[1];
  const float* Wk = (const float*)d_in[2];
  const float* Wv = (const float*)d_in[3];
  const float* Wo = (const float*)d_in[4];
  const float* ln1w = (const float*)d_in[5];
  const float* ln1b = (const float*)d_in[6];
  const float* ln2w = (const float*)d_in[7];
  const float* ln2b = (const float*)d_in[8];
  const float* f1w1 = (const float*)d_in[9];
  const float* f1b1 = (const float*)d_in[10];
  const float* f1w2 = (const float*)d_in[11];
  const float* f1b2 = (const float*)d_in[12];
  const float* f2w1 = (const float*)d_in[13];
  const float* f2b1 = (const float*)d_in[14];
  const float* f2w2 = (const float*)d_in[15];
  const float* f2b2 = (const float*)d_in[16];
  float* out = (float*)d_out;
  char* ws = (char*)d_ws;

  const size_t MB = 1024 * 1024;
  dim3 blk(256);

  // ws layout (peak 136 MiB, proven available by round-5 run):
  //   wqkv   [0,6)    wo [6,8)                      (phase-1 weights, bf16)
  //   xs     [8,40)   -> out1 (bf16) after QKV      (16384 x 1024)
  //   qkv    [40,136)                               (16384 x 3072)
  //   phase 2: fw [40,56), outs [56,72), hb [72,104); out1 persists [8,40)
  short* wqkv = (short*)ws;
  short* wo = (short*)(ws + 6 * MB);
  short* xs = (short*)(ws + 8 * MB);
  short* out1 = xs;  // overwrites xs (dead after QKV GEMM)
  short* qkvb = (short*)(ws + 40 * MB);

  // ---- Phase 1 -----------------------------------------------------------
  {
    Src4 s{{Wq, Wk, Wv, Wo}};
    cvt4_kernel<<<2048, blk, 0, stream>>>(s, wqkv, 17);  // 4 x 1M elems
  }
  ln_kernel<0><<<8192, blk, 0, stream>>>(input, ln1w, ln1b, xs);
  {
    dim3 g(24, 128);
    gemm_bt<0, 0><<<g, blk, 0, stream>>>(xs, 1024, wqkv, 1024, qkvb, 3072,
                                         nullptr, 0, nullptr, nullptr, 0,
                                         nullptr, nullptr, 0, 0);
  }
  attn_kernel<<<4096, blk, 0, stream>>>(qkvb);
  {
    dim3 g(8, 128);
    // out1 = concat @ Wo^T + input  -> bf16 (overwrites xs)
    gemm_bt<1, 0><<<g, blk, 0, stream>>>(qkvb, 3072, wo, 1024, out1, 1024,
                                         input, 1024, nullptr, nullptr, 0,
                                         nullptr, nullptr, 0, 0);
  }

  // ---- Phase 2 -----------------------------------------------------------
  short* fw1s0 = (short*)(ws + 40 * MB);
  short* fw1s1 = (short*)(ws + 44 * MB);
  short* fw2s0 = (short*)(ws + 48 * MB);
  short* fw2s1 = (short*)(ws + 52 * MB);
  short* outs = (short*)(ws + 56 * MB);  // 4096 x 2048 bf16 per chunk
  short* hb = (short*)(ws + 72 * MB);    // 4096 x 4096 bf16 per chunk
  {
    Src4 s{{f1w1, f2w1, f1w2, f2w2}};
    cvt4_kernel<<<4096, blk, 0, stream>>>(s, fw1s0, 18);  // 4 x 2M elems
  }
  const int CH = 4096;  // batches per chunk
  for (int b0 = 0; b0 < 8192; b0 += CH) {
    short* out1_c = out1 + (size_t)b0 * 2048;
    float* out_c = out + (size_t)b0 * 2048;
    ln_kernel<1><<<CH, blk, 0, stream>>>(out1_c, ln2w, ln2b, outs);
    // h_s = tanh(outs_s @ w1_s^T + b1_s): M=CH, N=2048, K=1024, z=s
    dim3 g1(16, CH / 128, 2);
    gemm_bt<2, 1><<<g1, blk, 0, stream>>>(
        outs, 2048, fw1s0, 1024, hb, 4096, nullptr, 0, f1b1, nullptr, 0,
        fw1s1, f2b1, /*a_zoff=*/1024, /*c_zoff=*/2048);
    // out_s = tanh(h_s @ w2_s^T + b2_s) + out1_s  (fp32 -> d_out)
    dim3 g2(8, CH / 128, 2);
    gemm_bt<3, 1><<<g2, blk, 0, stream>>>(
        hb, 4096, fw2s0, 2048, out_c, 2048, nullptr, 0, f1b2, out1_c, 2048,
        fw2s1, f2b2, /*a_zoff=*/2048, /*c_zoff=*/1024);
  }
}

// Round 8
// 548.846 us; speedup vs baseline: 2.3972x; 1.0394x over previous
//
#include <hip/hip_runtime.h>
#include <hip/hip_bf16.h>
#include <stdint.h>

// ---------------------------------------------------------------------------
// InterFusion, fp32 I/O: LN1 -> QKV(fused N=3072) -> attn(S=2) ->
// O-proj(+resid -> out1 bf16 in ws) -> LN2 -> FFN1 -> FFN2(+resid -> fp32 out).
// bf16 MFMA 16x16x32, fp32 acc; global_load_lds(16B) staging, XOR-swizzled
// LDS (0 conflicts); SGPR staging addressing + launch_bounds(256,4) -> 4
// blocks/CU. This round: phase 2 unchunked (outs lives in d_out as bf16),
// grids = exact residency multiples, 9 dispatches.
// ---------------------------------------------------------------------------

typedef __attribute__((ext_vector_type(8))) short short8;   // 8 bf16 = 4 VGPR
typedef __attribute__((ext_vector_type(4))) float floatx4;  // MFMA acc

__device__ __forceinline__ float b2f(short s) {
  union { unsigned u; float f; } v;
  v.u = ((unsigned)(unsigned short)s) << 16;
  return v.f;
}
__device__ __forceinline__ short f2b(float f) {
  union { float f; unsigned u; } v;
  v.f = f;
  unsigned r = v.u + 0x7FFFu + ((v.u >> 16) & 1u);  // RNE
  return (short)(r >> 16);
}
__device__ __forceinline__ float fast_tanh(float x) {
  float e = __expf(2.f * x);
  return 1.f - 2.f / (e + 1.f);
}
__device__ __forceinline__ void load16_lds(const void* g, void* l) {
  __builtin_amdgcn_global_load_lds(
      (__attribute__((address_space(1))) void*)(void*)g,
      (__attribute__((address_space(3))) void*)l, 16, 0, 0);
}

// ---------------------------------------------------------------------------
// 4-source fp32 -> bf16 conversion into one contiguous bf16 region.
// per-source element count = 8 << sh; one thread converts 8 elems.
// ---------------------------------------------------------------------------
struct Src4 { const float* p[4]; };

__global__ __launch_bounds__(256) void cvt4_kernel(Src4 s,
                                                   short* __restrict__ y,
                                                   int sh) {
  const int i = blockIdx.x * 256 + threadIdx.x;  // global 8-elem index
  const int seg = i >> sh;
  const int off = i & ((1 << sh) - 1);
  const float* x = s.p[seg];
  const float4 a = ((const float4*)x)[(size_t)off * 2];
  const float4 b = ((const float4*)x)[(size_t)off * 2 + 1];
  short8 r;
  r[0] = f2b(a.x); r[1] = f2b(a.y); r[2] = f2b(a.z); r[3] = f2b(a.w);
  r[4] = f2b(b.x); r[5] = f2b(b.y); r[6] = f2b(b.z); r[7] = f2b(b.w);
  ((short8*)y)[i] = r;
}

// ---------------------------------------------------------------------------
// GEMM: C[M,N] = A[M,K] @ W[N,K]^T  (bf16 in, fp32 acc).
// grid = (N/128, M/128, ZSEL?2:1), block = 256 (4 waves, 2x2 of 64x64).
// Staging: global_load_lds 16B/lane; lane loads k-granule (lane&7)^(row&7);
// reads use ko=(gk^(row&7))*8. Wave-uniform SGPR base per issue + one
// per-lane 32-bit offset (VGPR<=64 -> 4 blocks/CU).
// EPI 0: store bf16
// EPI 1: c + aux_f32[r][n], store bf16            (out1 = Oproj + input)
// EPI 2: tanh(c + bias[n]), store bf16            (FFN hidden)
// EPI 3: tanh(c + bias[n]) + b2f(res_bf16), store fp32   (final output)
// ZSEL: blockIdx.z==1 -> Wz/biasz, A += a_zoff, C/res += c_zoff.
// ---------------------------------------------------------------------------
template <int EPI, int ZSEL>
__global__ __launch_bounds__(256, 4) void gemm_bt(
    const short* A, int lda, const short* W, int K, void* Cout, int ldc,
    const float* aux, int ld_aux, const float* bias, const short* res, int ldr,
    const short* Wz, const float* biasz, int a_zoff, int c_zoff) {
  __shared__ short As[128 * 64];
  __shared__ short Bs[128 * 64];
  const int tid = threadIdx.x;
  const int lane = tid & 63;
  const int wid = tid >> 6;
  const int l15 = lane & 15;
  const int l4 = lane >> 4;
  const int wm = (wid >> 1) * 64;
  const int wn = (wid & 1) * 64;
  const int bn0 = blockIdx.x * 128;
  const int bm0 = blockIdx.y * 128;

  const short* Wp = W;
  const float* bp = bias;
  int coff = 0;
  if (ZSEL && blockIdx.z) {
    Wp = Wz;
    bp = biasz;
    A += a_zoff;
    coff = c_zoff;
  }

  floatx4 zero = {0.f, 0.f, 0.f, 0.f};
  floatx4 acc[4][4];
#pragma unroll
  for (int i = 0; i < 4; ++i)
#pragma unroll
    for (int j = 0; j < 4; ++j) acc[i][j] = zero;

  // staging: issue e covers rows e*8..e*8+7; lane -> row e*8+r8, loads
  // granule (lane&7)^r8 -> lands at LDS slot (lane&7) of its row.
  const int r8 = lane >> 3;
  const int gsw = (lane & 7) ^ r8;
  const int aoff = r8 * lda + gsw * 8;  // per-lane element offset (VGPR)
  const int boff = r8 * K + gsw * 8;
  const short* Ab = A + (size_t)bm0 * lda;    // wave-uniform
  const short* Bb = Wp + (size_t)bn0 * K;     // wave-uniform
  const int e0 = __builtin_amdgcn_readfirstlane(wid * 4);
  const int swz = l15 & 7;  // read-side swizzle key (= fragment row & 7)

  for (int k0 = 0; k0 < K; k0 += 64) {
#pragma unroll
    for (int t = 0; t < 4; ++t) {
      const int e = e0 + t;
      load16_lds(Ab + (size_t)e * 8 * lda + k0 + aoff, &As[e * 512]);
      load16_lds(Bb + (size_t)e * 8 * K + k0 + boff, &Bs[e * 512]);
    }
    __syncthreads();  // compiler drains vmcnt(0) before s_barrier
#pragma unroll
    for (int kk = 0; kk < 2; ++kk) {
      const int ko = ((kk * 4 + l4) ^ swz) * 8;
      short8 av[4], bv[4];
#pragma unroll
      for (int i = 0; i < 4; ++i) {
        av[i] = *(const short8*)&As[(wm + i * 16 + l15) * 64 + ko];
        bv[i] = *(const short8*)&Bs[(wn + i * 16 + l15) * 64 + ko];
      }
#pragma unroll
      for (int i = 0; i < 4; ++i)
#pragma unroll
        for (int j = 0; j < 4; ++j)
          acc[i][j] = __builtin_amdgcn_mfma_f32_16x16x32_bf16(av[i], bv[j],
                                                              acc[i][j], 0, 0, 0);
    }
    __syncthreads();
  }

  // epilogue: lane holds C[mb + i*16 + p][nb + j*16], p = 0..3
  const int mb = bm0 + wm + l4 * 4;
  const int nb = bn0 + wn + l15;
#pragma unroll
  for (int i = 0; i < 4; ++i) {
#pragma unroll
    for (int p = 0; p < 4; ++p) {
      const int r = mb + i * 16 + p;
#pragma unroll
      for (int j = 0; j < 4; ++j) {
        const int n = nb + j * 16;
        float c = acc[i][j][p];
        if (EPI == 0) {
          ((short*)Cout)[(size_t)r * ldc + n + coff] = f2b(c);
        } else if (EPI == 1) {
          ((short*)Cout)[(size_t)r * ldc + n + coff] =
              f2b(c + aux[(size_t)r * ld_aux + n]);
        } else if (EPI == 2) {
          ((short*)Cout)[(size_t)r * ldc + n + coff] =
              f2b(fast_tanh(c + bp[n]));
        } else {
          const float rv = b2f(res[(size_t)r * ldr + n + coff]);
          ((float*)Cout)[(size_t)r * ldc + n + coff] =
              fast_tanh(c + bp[n]) + rv;
        }
      }
    }
  }
}

// ---------------------------------------------------------------------------
// LayerNorm over (S,E) = 2048 elems per batch. One block per batch.
// INBF16 selects input dtype; output bf16. w/b fp32 (length 2048).
// ---------------------------------------------------------------------------
template <int INBF16>
__global__ __launch_bounds__(256) void ln_kernel(const void* __restrict__ xin,
                                                 const float* __restrict__ w,
                                                 const float* __restrict__ bb,
                                                 short* __restrict__ y) {
  const int b = blockIdx.x;
  const int tid = threadIdx.x;
  const size_t base = (size_t)b * 2048 + tid * 8;
  float xv[8];
  if (INBF16) {
    short8 s = *(const short8*)((const short*)xin + base);
#pragma unroll
    for (int j = 0; j < 8; ++j) xv[j] = b2f(s[j]);
  } else {
    const float4 a = *(const float4*)((const float*)xin + base);
    const float4 c = *(const float4*)((const float*)xin + base + 4);
    xv[0] = a.x; xv[1] = a.y; xv[2] = a.z; xv[3] = a.w;
    xv[4] = c.x; xv[5] = c.y; xv[6] = c.z; xv[7] = c.w;
  }
  float sum = 0.f, sq = 0.f;
#pragma unroll
  for (int j = 0; j < 8; ++j) {
    sum += xv[j];
    sq += xv[j] * xv[j];
  }
  __shared__ float rs[8];
  const int lane = tid & 63, wid = tid >> 6;
#pragma unroll
  for (int off = 32; off; off >>= 1) {
    sum += __shfl_down(sum, off);
    sq += __shfl_down(sq, off);
  }
  if (lane == 0) {
    rs[wid] = sum;
    rs[4 + wid] = sq;
  }
  __syncthreads();
  const float stot = rs[0] + rs[1] + rs[2] + rs[3];
  const float qtot = rs[4] + rs[5] + rs[6] + rs[7];
  const float mean = stot * (1.f / 2048.f);
  const float rstd = rsqrtf(qtot * (1.f / 2048.f) - mean * mean + 1e-5f);
  const int wi = tid * 8;
  short8 r;
#pragma unroll
  for (int j = 0; j < 8; ++j)
    r[j] = f2b((xv[j] - mean) * rstd * w[wi + j] + bb[wi + j]);
  *(short8*)(y + base) = r;
}

// ---------------------------------------------------------------------------
// Attention, S=2, on the fused QKV buffer (row stride 3072: q|k|v columns).
// q[b,h,s,d] = qkv[b*2+s][d*16+h]; scores (2x2)/8; softmax over t;
// concat[b,s,e] = p0*v[b,0,e] + p1*v[b,1,e], h = e&15. Overwrites q cols.
// Block=256 handles 2 b's (128 threads each).
// ---------------------------------------------------------------------------
__global__ __launch_bounds__(256) void attn_kernel(short* qkv) {
  __shared__ short sm[2][6][1032];    // q0,q1,k0,k1,v0,v1
  __shared__ float sps[2][2][2][16];  // [half][s][t][h] scores
  __shared__ float spp[2][2][2][16];  // [half][s][t][h] probs
  const int tid = threadIdx.x;
  const int half = tid >> 7;
  const int t = tid & 127;
  const int b = blockIdx.x * 2 + half;
  const short* row0 = qkv + ((size_t)b * 2 + 0) * 3072;
  const short* row1 = qkv + ((size_t)b * 2 + 1) * 3072;
  const short* srcs[6] = {row0,        row1,        row0 + 1024,
                          row1 + 1024, row0 + 2048, row1 + 2048};
#pragma unroll
  for (int rr = 0; rr < 6; ++rr)
    *(short8*)&sm[half][rr][t * 8] = *(const short8*)(srcs[rr] + t * 8);
  __syncthreads();
  if (t < 64) {
    const int h = t & 15, comb = t >> 4;
    const int si = comb >> 1, ti = comb & 1;
    const short* qr = sm[half][si];
    const short* kr = sm[half][2 + ti];
    float a = 0.f;
#pragma unroll
    for (int d = 0; d < 64; ++d) a += b2f(qr[d * 16 + h]) * b2f(kr[d * 16 + h]);
    sps[half][si][ti][h] = a * 0.125f;  // / sqrt(NH=64)
  }
  __syncthreads();
  if (t < 32) {
    const int h = t & 15, si = t >> 4;
    const float s0 = sps[half][si][0][h], s1 = sps[half][si][1][h];
    const float m = fmaxf(s0, s1);
    const float e0 = __expf(s0 - m), e1 = __expf(s1 - m);
    const float inv = 1.f / (e0 + e1);
    spp[half][si][0][h] = e0 * inv;
    spp[half][si][1][h] = e1 * inv;
  }
  __syncthreads();
#pragma unroll
  for (int si = 0; si < 2; ++si) {
    short8 r;
#pragma unroll
    for (int j = 0; j < 8; ++j) {
      const int e = t * 8 + j;
      const int h = e & 15;
      const float c = spp[half][si][0][h] * b2f(sm[half][4][e]) +
                      spp[half][si][1][h] * b2f(sm[half][5][e]);
      r[j] = f2b(c);
    }
    *(short8*)(qkv + ((size_t)b * 2 + si) * 3072 + t * 8) = r;
  }
}

// ---------------------------------------------------------------------------
extern "C" void kernel_launch(void* const* d_in, const int* in_sizes, int n_in,
                              void* d_out, int out_size, void* d_ws,
                              size_t ws_size, hipStream_t stream) {
  (void)in_sizes; (void)n_in; (void)out_size; (void)ws_size;
  const float* input = (const float*)d_in[0];
  const float* Wq = (const float*)d_in[1];
  const float* Wk = (const float*)d_in[2];
  const float* Wv = (const float*)d_in[3];
  const float* Wo = (const float*)d_in[4];
  const float* ln1w = (const float*)d_in[5];
  const float* ln1b = (const float*)d_in[6];
  const float* ln2w = (const float*)d_in[7];
  const float* ln2b = (const float*)d_in[8];
  const float* f1w1 = (const float*)d_in[9];
  const float* f1b1 = (const float*)d_in[10];
  const float* f1w2 = (const float*)d_in[11];
  const float* f1b2 = (const float*)d_in[12];
  const float* f2w1 = (const float*)d_in[13];
  const float* f2b1 = (const float*)d_in[14];
  const float* f2w2 = (const float*)d_in[15];
  const float* f2b2 = (const float*)d_in[16];
  float* out = (float*)d_out;
  char* ws = (char*)d_ws;

  const size_t MB = 1024 * 1024;
  dim3 blk(256);

  // ws layout:
  //   phase 1: wqkv+wo [0,8) | xs->out1 [8,40) | qkv [40,136)   (136 MiB)
  //   phase 2: out1 [8,40) | fw [40,56) | hb [56,120)            (120 MiB)
  //   outs (LN2 output, 8192x2048 bf16 = 32 MiB) lives in d_out; safe by
  //   stream order: LN2 writes it, FFN1 consumes it, FFN2 overwrites d_out.
  short* wqkv = (short*)ws;
  short* wo = (short*)(ws + 6 * MB);
  short* xs = (short*)(ws + 8 * MB);
  short* out1 = xs;  // overwrites xs (dead after QKV GEMM)
  short* qkvb = (short*)(ws + 40 * MB);

  // ---- Phase 1 -----------------------------------------------------------
  {
    Src4 s{{Wq, Wk, Wv, Wo}};
    cvt4_kernel<<<2048, blk, 0, stream>>>(s, wqkv, 17);  // 4 x 1M elems
  }
  ln_kernel<0><<<8192, blk, 0, stream>>>(input, ln1w, ln1b, xs);
  {
    dim3 g(24, 128);  // 3072 blocks = 3 residency waves
    gemm_bt<0, 0><<<g, blk, 0, stream>>>(xs, 1024, wqkv, 1024, qkvb, 3072,
                                         nullptr, 0, nullptr, nullptr, 0,
                                         nullptr, nullptr, 0, 0);
  }
  attn_kernel<<<4096, blk, 0, stream>>>(qkvb);
  {
    dim3 g(8, 128);  // 1024 blocks = 1 residency wave
    // out1 = concat @ Wo^T + input  -> bf16 (overwrites xs)
    gemm_bt<1, 0><<<g, blk, 0, stream>>>(qkvb, 3072, wo, 1024, out1, 1024,
                                         input, 1024, nullptr, nullptr, 0,
                                         nullptr, nullptr, 0, 0);
  }

  // ---- Phase 2 (unchunked) ----------------------------------------------
  short* fw1s0 = (short*)(ws + 40 * MB);
  short* fw1s1 = (short*)(ws + 44 * MB);
  short* fw2s0 = (short*)(ws + 48 * MB);
  short* fw2s1 = (short*)(ws + 52 * MB);
  short* hb = (short*)(ws + 56 * MB);  // 8192 x 4096 bf16 (64 MiB)
  short* outs = (short*)out;           // d_out reused as bf16 LN2 output
  {
    Src4 s{{f1w1, f2w1, f1w2, f2w2}};
    cvt4_kernel<<<4096, blk, 0, stream>>>(s, fw1s0, 18);  // 4 x 2M elems
  }
  ln_kernel<1><<<8192, blk, 0, stream>>>(out1, ln2w, ln2b, outs);
  {
    // h_s = tanh(outs_s @ w1_s^T + b1_s): M=8192, N=2048, K=1024, z=s
    dim3 g1(16, 64, 2);  // 2048 blocks = 2 residency waves
    gemm_bt<2, 1><<<g1, blk, 0, stream>>>(
        outs, 2048, fw1s0, 1024, hb, 4096, nullptr, 0, f1b1, nullptr, 0,
        fw1s1, f2b1, /*a_zoff=*/1024, /*c_zoff=*/2048);
    // out_s = tanh(h_s @ w2_s^T + b2_s) + out1_s  (fp32 -> d_out)
    dim3 g2(8, 64, 2);  // 1024 blocks = 1 residency wave
    gemm_bt<3, 1><<<g2, blk, 0, stream>>>(
        hb, 4096, fw2s0, 2048, out, 2048, nullptr, 0, f1b2, out1, 2048,
        fw2s1, f2b2, /*a_zoff=*/2048, /*c_zoff=*/1024);
  }
}